// Round 1
// baseline (40521.182 us; speedup 1.0000x reference)
//
#include <hip/hip_runtime.h>
#include <math.h>

#define V 13000
#define D 300
#define M 500
#define B 64
#define NW 5
#define T 128
#define NSUP (B*NW)      // 320
#define NSEQ (NSUP + B)  // 384
#define GOUT (3*M)       // 1500

__device__ __forceinline__ float sigmoidf_(float x){ return 1.0f/(1.0f+expf(-x)); }

// One block per chain (seq, dir). dir 0 = left scan (steps = blank),
// dir 1 = right scan over reversed tokens (steps = T-1-blank).
__global__ void scan_kernel(const int* __restrict__ sup_tok, const int* __restrict__ tgt_tok,
                            const int* __restrict__ blank_sup, const int* __restrict__ blank_tgt,
                            const float* __restrict__ emb,
                            const float* __restrict__ WL, const float* __restrict__ UL, const float* __restrict__ bL,
                            const float* __restrict__ WR, const float* __restrict__ UR, const float* __restrict__ bR,
                            const float* __restrict__ c0L, const float* __restrict__ c0R,
                            float* __restrict__ l_out, float* __restrict__ r_out)
{
    __shared__ __align__(16) float c[M];
    __shared__ __align__(16) float x[304];
    __shared__ float g[GOUT];

    const int chain = blockIdx.x;
    const int dir = chain & 1;
    const int seq = chain >> 1;
    const int tid = threadIdx.x;

    const int* toks; int blank;
    if (seq < NSUP) { toks = sup_tok + seq*T; blank = blank_sup[seq]; }
    else            { toks = tgt_tok + (seq-NSUP)*T; blank = blank_tgt[seq-NSUP]; }

    const float *W, *U, *bias, *c0; float* out; int nsteps;
    if (dir == 0) { W=WL; U=UL; bias=bL; c0=c0L; out=l_out + seq*M; nsteps = blank; }
    else          { W=WR; U=UR; bias=bR; c0=c0R; out=r_out + seq*M; nsteps = T-1-blank; }

    for (int m=tid; m<M; m+=blockDim.x) c[m] = c0[m];
    __syncthreads();

    for (int s=0; s<nsteps; ++s) {
        const int tpos = (dir==0) ? s : (T-1-s);
        const int tok = toks[tpos];
        for (int d=tid; d<D; d+=blockDim.x) x[d] = emb[tok*D + d];
        __syncthreads();

        for (int o=tid; o<GOUT; o+=blockDim.x) {
            const float4* Wrow = reinterpret_cast<const float4*>(W + (size_t)o*D);
            const float4* xv   = reinterpret_cast<const float4*>(x);
            float acc = bias[o];
            #pragma unroll 5
            for (int q=0; q<D/4; ++q) {
                float4 w = Wrow[q], xx = xv[q];
                acc += w.x*xx.x + w.y*xx.y + w.z*xx.z + w.w*xx.w;
            }
            const float4* Urow = reinterpret_cast<const float4*>(U + (size_t)o*M);
            const float4* cv   = reinterpret_cast<const float4*>(c);
            #pragma unroll 5
            for (int q=0; q<M/4; ++q) {
                float4 u = Urow[q], cc = cv[q];
                acc += u.x*cc.x + u.y*cc.y + u.z*cc.z + u.w*cc.w;
            }
            g[o] = acc;
        }
        __syncthreads();

        for (int m=tid; m<M; m+=blockDim.x) {
            float f  = sigmoidf_(g[m]);
            float i  = sigmoidf_(g[M+m]);
            float cb = tanhf(g[2*M+m]);
            c[m] = f*c[m] + i*cb;
        }
        __syncthreads();
    }

    for (int m=tid; m<M; m+=blockDim.x) out[m] = c[m];
}

// env[i][d] = tanh( sum_m l[i][m]*Wo[d][m] + r[i][m]*Uo[d][m] + bo[d] )
__global__ void env_kernel(const float* __restrict__ l_states, const float* __restrict__ r_states,
                           const float* __restrict__ Wo, const float* __restrict__ Uo,
                           const float* __restrict__ bo,
                           float* __restrict__ env)
{
    __shared__ __align__(16) float l[M];
    __shared__ __align__(16) float r[M];
    const int i = blockIdx.x;
    const int tid = threadIdx.x;
    for (int m=tid; m<M; m+=blockDim.x){ l[m]=l_states[i*M+m]; r[m]=r_states[i*M+m]; }
    __syncthreads();
    for (int d=tid; d<D; d+=blockDim.x) {
        const float4* wo = reinterpret_cast<const float4*>(Wo + (size_t)d*M);
        const float4* uo = reinterpret_cast<const float4*>(Uo + (size_t)d*M);
        const float4* lv = reinterpret_cast<const float4*>(l);
        const float4* rv = reinterpret_cast<const float4*>(r);
        float acc = bo[d];
        #pragma unroll 5
        for (int q=0; q<M/4; ++q) {
            float4 a=wo[q], bv=lv[q], u=uo[q], rr=rv[q];
            acc += a.x*bv.x + a.y*bv.y + a.z*bv.z + a.w*bv.w;
            acc += u.x*rr.x + u.y*rr.y + u.z*rr.z + u.w*rr.w;
        }
        env[i*D + d] = tanhf(acc);
    }
}

// One block (1 wave) per episode: cosine sims, softmax, argmax flag + loss term.
__global__ void episode_kernel(const float* __restrict__ env, const int* __restrict__ target_y,
                               float* __restrict__ flags, float* __restrict__ losses)
{
    const int b = blockIdx.x;
    const int lane = threadIdx.x;
    const float* tgt = env + (size_t)(NSUP + b)*D;

    float tn = 0.f;
    for (int d=lane; d<D; d+=64){ float v=tgt[d]; tn += v*v; }
    for (int off=32; off; off>>=1) tn += __shfl_down(tn, off);
    tn = __shfl(tn, 0);

    float z[NW];
    for (int n=0; n<NW; ++n){
        const float* sup = env + (size_t)(b*NW + n)*D;
        float dot=0.f, sn=0.f;
        for (int d=lane; d<D; d+=64){ float sv=sup[d], tv=tgt[d]; dot+=sv*tv; sn+=sv*sv; }
        for (int off=32; off; off>>=1){ dot += __shfl_down(dot,off); sn += __shfl_down(sn,off); }
        dot = __shfl(dot,0); sn = __shfl(sn,0);
        float denom = fmaxf(sqrtf(sn)*sqrtf(tn), 1e-8f);
        z[n] = dot/denom*10.0f;
    }

    if (lane==0){
        float mx=z[0];
        for(int n=1;n<NW;n++) mx=fmaxf(mx,z[n]);
        float se=0.f; float p[NW];
        for(int n=0;n<NW;n++){ p[n]=expf(z[n]-mx); se+=p[n]; }
        for(int n=0;n<NW;n++) p[n]/=se;
        int am=0; float bv=p[0];
        for(int n=1;n<NW;n++) if(p[n]>bv){bv=p[n];am=n;}
        int y = target_y[b];
        flags[b] = (am==y)?1.0f:0.0f;
        float mx2=p[0]; for(int n=1;n<NW;n++) mx2=fmaxf(mx2,p[n]);
        float se2=0.f; for(int n=0;n<NW;n++) se2+=expf(p[n]-mx2);
        losses[b] = -(p[y]-mx2-logf(se2));
    }
}

__global__ void finalize_kernel(const float* __restrict__ flags, const float* __restrict__ losses,
                                float* __restrict__ out)
{
    const int lane = threadIdx.x; // 64 threads
    float f = flags[lane], l = losses[lane];
    for (int off=32; off; off>>=1){ f += __shfl_down(f,off); l += __shfl_down(l,off); }
    if (lane==0){ out[0] = f/(float)B; out[1] = l/(float)B; }
}

extern "C" void kernel_launch(void* const* d_in, const int* in_sizes, int n_in,
                              void* d_out, int out_size, void* d_ws, size_t ws_size,
                              hipStream_t stream) {
    const int*   sup_tok   = (const int*)d_in[0];
    const int*   tgt_tok   = (const int*)d_in[1];
    const int*   blank_sup = (const int*)d_in[2];
    const int*   blank_tgt = (const int*)d_in[3];
    const int*   target_y  = (const int*)d_in[4];
    const float* emb = (const float*)d_in[5];
    const float* WL  = (const float*)d_in[6];
    const float* UL  = (const float*)d_in[7];
    const float* bL  = (const float*)d_in[8];
    const float* WR  = (const float*)d_in[9];
    const float* UR  = (const float*)d_in[10];
    const float* bR  = (const float*)d_in[11];
    const float* Wo  = (const float*)d_in[12];
    const float* Uo  = (const float*)d_in[13];
    const float* bo  = (const float*)d_in[14];
    const float* c0L = (const float*)d_in[15];
    const float* c0R = (const float*)d_in[16];

    float* ws = (float*)d_ws;
    float* l_states = ws;                      // [NSEQ*M]
    float* r_states = l_states + NSEQ*M;       // [NSEQ*M]
    float* env      = r_states + NSEQ*M;       // [NSEQ*D]
    float* flags    = env + NSEQ*D;            // [B]
    float* losses   = flags + B;               // [B]

    scan_kernel<<<NSEQ*2, 256, 0, stream>>>(sup_tok, tgt_tok, blank_sup, blank_tgt,
                                            emb, WL, UL, bL, WR, UR, bR, c0L, c0R,
                                            l_states, r_states);
    env_kernel<<<NSEQ, 256, 0, stream>>>(l_states, r_states, Wo, Uo, bo, env);
    episode_kernel<<<B, 64, 0, stream>>>(env, target_y, flags, losses);
    finalize_kernel<<<1, 64, 0, stream>>>(flags, losses, (float*)d_out);
}

// Round 2
// 11012.658 us; speedup vs baseline: 3.6795x; 3.6795x over previous
//
#include <hip/hip_runtime.h>
#include <math.h>

#define V 13000
#define D 300
#define M 500
#define B 64
#define NW 5
#define T 128
#define NSUP (B*NW)      // 320
#define NSEQ (NSUP + B)  // 384
#define CT 64            // chains per tile
#define NCT 6            // 384/64
#define MT 16            // m per block
#define NMT 32           // ceil(500/16)
#define KTOT 800         // D + M
#define CHUNK 100        // K chunk
#define NCHUNK 8         // 3 x-chunks + 5 c-chunks

__device__ __forceinline__ float sigmoidf_(float x){ return 1.0f/(1.0f+expf(-x)); }

// -------- prologue: init c buffers / c_final to c0 --------
__global__ void init_c_kernel(const float* __restrict__ c0L, const float* __restrict__ c0R,
                              float* __restrict__ cA, float* __restrict__ cfin)
{
    int idx = blockIdx.x*256 + threadIdx.x;           // 2*384*500 = 384000
    if (idx >= 2*NSEQ*M) return;
    int m = idx % M;
    int dir = idx / (NSEQ*M);
    float v = dir ? c0R[m] : c0L[m];
    cA[idx] = v;
    cfin[idx] = v;
}

// -------- prologue: per-dir lengths + descending rank sort + tile maxes --------
__global__ void sort_kernel(const int* __restrict__ blank_sup, const int* __restrict__ blank_tgt,
                            int* __restrict__ perm, int* __restrict__ lens, int* __restrict__ tmax)
{
    __shared__ int L0[NSEQ], L1[NSEQ];
    int tid = threadIdx.x;                            // 384 threads
    int blank = (tid < NSUP) ? blank_sup[tid] : blank_tgt[tid - NSUP];
    int l0 = blank, l1 = (T-1) - blank;
    L0[tid] = l0; L1[tid] = l1;
    lens[tid] = l0; lens[NSEQ + tid] = l1;
    __syncthreads();
    int r0 = 0, r1 = 0;
    for (int j = 0; j < NSEQ; ++j) {
        int c = L0[j]; r0 += (c > l0) || (c == l0 && j < tid);
        int d = L1[j]; r1 += (d > l1) || (d == l1 && j < tid);
    }
    perm[r0] = tid;
    perm[NSEQ + r1] = tid;
    __syncthreads();
    if (tid < 2*NCT) {
        int dir = tid / NCT, t = tid % NCT;
        int first = perm[dir*NSEQ + t*CT];            // descending sort -> first is max
        tmax[tid] = lens[dir*NSEQ + first];
    }
}

// -------- per-step fused gates+update kernel --------
__global__ __launch_bounds__(256)
void step_kernel(int s,
                 const float* __restrict__ c_src, float* __restrict__ c_dst,
                 float* __restrict__ c_final,
                 const float* __restrict__ WL, const float* __restrict__ UL, const float* __restrict__ bL,
                 const float* __restrict__ WR, const float* __restrict__ UR, const float* __restrict__ bR,
                 const int* __restrict__ perm, const int* __restrict__ lens, const int* __restrict__ tmax,
                 const int* __restrict__ sup_tok, const int* __restrict__ tgt_tok,
                 const float* __restrict__ emb)
{
    const int bid = blockIdx.x;                       // 2*NCT*NMT = 384
    const int dir = bid / (NCT*NMT);
    const int rem = bid % (NCT*NMT);
    const int ctile = rem / NMT;
    const int mtile = rem % NMT;
    if (s >= tmax[dir*NCT + ctile]) return;           // whole chain-tile finished

    __shared__ float4 act[CHUNK/4][CT];               // transposed: [qf][chain] -> 2-way banks
    __shared__ int chain_s[CT], len_s[CT], tok_s[CT];

    const int tid = threadIdx.x;
    if (tid < CT) {
        int p = ctile*CT + tid;
        int ch = perm[dir*NSEQ + p];
        chain_s[tid] = ch;
        len_s[tid] = lens[dir*NSEQ + ch];
        int tpos = dir ? ((T-1) - s) : s;
        tok_s[tid] = (ch < NSUP) ? sup_tok[ch*T + tpos] : tgt_tok[(ch - NSUP)*T + tpos];
    }
    __syncthreads();

    const int mi = tid >> 4;                          // 0..15
    const int cg = tid & 15;                          // 0..15
    const int m  = mtile*MT + mi;
    const bool mvalid = (m < M);

    const float* Wd = dir ? WR : WL;
    const float* Ud = dir ? UR : UL;
    const float* bias = dir ? bR : bL;

    float a0[4], a1[4], a2[4];
    {
        float b0 = 0.f, b1 = 0.f, b2 = 0.f;
        if (mvalid) { b0 = bias[m]; b1 = bias[M + m]; b2 = bias[2*M + m]; }
        #pragma unroll
        for (int k = 0; k < 4; ++k) { a0[k] = b0; a1[k] = b1; a2[k] = b2; }
    }

    for (int kc = 0; kc < NCHUNK; ++kc) {
        // ---- stage 64 chains x 100 floats into LDS (transposed) ----
        #pragma unroll
        for (int it = 0; it < 7; ++it) {
            int fidx = it*256 + tid;                  // 1600 float4 total
            if (fidx < CT*(CHUNK/4)) {
                int row = fidx / (CHUNK/4);
                int qf  = fidx % (CHUNK/4);
                const float* src;
                if (kc < 3) src = emb + (size_t)tok_s[row]*D + kc*CHUNK + qf*4;
                else        src = c_src + ((size_t)dir*NSEQ + chain_s[row])*M + (kc-3)*CHUNK + qf*4;
                act[qf][row] = *(const float4*)src;
            }
        }
        __syncthreads();

        if (mvalid) {
            const float *w0, *w1, *w2;
            if (kc < 3) {
                const float* base = Wd + (size_t)m*D + kc*CHUNK;
                w0 = base; w1 = base + (size_t)M*D; w2 = base + (size_t)2*M*D;
            } else {
                const float* base = Ud + (size_t)m*M + (kc-3)*CHUNK;
                w0 = base; w1 = base + (size_t)M*M; w2 = base + (size_t)2*M*M;
            }
            for (int qf = 0; qf < CHUNK/4; ++qf) {
                float4 W0 = *(const float4*)(w0 + qf*4);
                float4 W1 = *(const float4*)(w1 + qf*4);
                float4 W2 = *(const float4*)(w2 + qf*4);
                #pragma unroll
                for (int k = 0; k < 4; ++k) {
                    float4 A = act[qf][cg + 16*k];
                    a0[k] += W0.x*A.x + W0.y*A.y + W0.z*A.z + W0.w*A.w;
                    a1[k] += W1.x*A.x + W1.y*A.y + W1.z*A.z + W1.w*A.w;
                    a2[k] += W2.x*A.x + W2.y*A.y + W2.z*A.z + W2.w*A.w;
                }
            }
        }
        __syncthreads();
    }

    if (mvalid) {
        #pragma unroll
        for (int k = 0; k < 4; ++k) {
            int r = cg + 16*k;
            int ch = chain_s[r];
            int L  = len_s[r];
            size_t idx = ((size_t)dir*NSEQ + ch)*M + m;
            float cold = c_src[idx];
            if (s < L) {
                float f  = sigmoidf_(a0[k]);
                float i2 = sigmoidf_(a1[k]);
                float cb = tanhf(a2[k]);
                float cn = f*cold + i2*cb;
                c_dst[idx] = cn;
                if (s == L-1) c_final[idx] = cn;      // state after L steps
            } else {
                c_dst[idx] = cold;                    // frozen chain: carry forward
            }
        }
    }
}

// -------- epilogue: env = tanh(l@Wo^T + r@Uo^T + bo) --------
__global__ void env_kernel(const float* __restrict__ l_states, const float* __restrict__ r_states,
                           const float* __restrict__ Wo, const float* __restrict__ Uo,
                           const float* __restrict__ bo,
                           float* __restrict__ env)
{
    __shared__ __align__(16) float l[M];
    __shared__ __align__(16) float r[M];
    const int i = blockIdx.x;
    const int tid = threadIdx.x;
    for (int m=tid; m<M; m+=blockDim.x){ l[m]=l_states[i*M+m]; r[m]=r_states[i*M+m]; }
    __syncthreads();
    for (int d=tid; d<D; d+=blockDim.x) {
        const float4* wo = reinterpret_cast<const float4*>(Wo + (size_t)d*M);
        const float4* uo = reinterpret_cast<const float4*>(Uo + (size_t)d*M);
        const float4* lv = reinterpret_cast<const float4*>(l);
        const float4* rv = reinterpret_cast<const float4*>(r);
        float acc = bo[d];
        #pragma unroll 5
        for (int q=0; q<M/4; ++q) {
            float4 a=wo[q], bv=lv[q], u=uo[q], rr=rv[q];
            acc += a.x*bv.x + a.y*bv.y + a.z*bv.z + a.w*bv.w;
            acc += u.x*rr.x + u.y*rr.y + u.z*rr.z + u.w*rr.w;
        }
        env[i*D + d] = tanhf(acc);
    }
}

__global__ void episode_kernel(const float* __restrict__ env, const int* __restrict__ target_y,
                               float* __restrict__ flags, float* __restrict__ losses)
{
    const int b = blockIdx.x;
    const int lane = threadIdx.x;
    const float* tgt = env + (size_t)(NSUP + b)*D;

    float tn = 0.f;
    for (int d=lane; d<D; d+=64){ float v=tgt[d]; tn += v*v; }
    for (int off=32; off; off>>=1) tn += __shfl_down(tn, off);
    tn = __shfl(tn, 0);

    float z[NW];
    for (int n=0; n<NW; ++n){
        const float* sup = env + (size_t)(b*NW + n)*D;
        float dot=0.f, sn=0.f;
        for (int d=lane; d<D; d+=64){ float sv=sup[d], tv=tgt[d]; dot+=sv*tv; sn+=sv*sv; }
        for (int off=32; off; off>>=1){ dot += __shfl_down(dot,off); sn += __shfl_down(sn,off); }
        dot = __shfl(dot,0); sn = __shfl(sn,0);
        float denom = fmaxf(sqrtf(sn)*sqrtf(tn), 1e-8f);
        z[n] = dot/denom*10.0f;
    }

    if (lane==0){
        float mx=z[0];
        for(int n=1;n<NW;n++) mx=fmaxf(mx,z[n]);
        float se=0.f; float p[NW];
        for(int n=0;n<NW;n++){ p[n]=expf(z[n]-mx); se+=p[n]; }
        for(int n=0;n<NW;n++) p[n]/=se;
        int am=0; float bv=p[0];
        for(int n=1;n<NW;n++) if(p[n]>bv){bv=p[n];am=n;}
        int y = target_y[b];
        flags[b] = (am==y)?1.0f:0.0f;
        float mx2=p[0]; for(int n=1;n<NW;n++) mx2=fmaxf(mx2,p[n]);
        float se2=0.f; for(int n=0;n<NW;n++) se2+=expf(p[n]-mx2);
        losses[b] = -(p[y]-mx2-logf(se2));
    }
}

__global__ void finalize_kernel(const float* __restrict__ flags, const float* __restrict__ losses,
                                float* __restrict__ out)
{
    const int lane = threadIdx.x; // 64 threads
    float f = flags[lane], l = losses[lane];
    for (int off=32; off; off>>=1){ f += __shfl_down(f,off); l += __shfl_down(l,off); }
    if (lane==0){ out[0] = f/(float)B; out[1] = l/(float)B; }
}

extern "C" void kernel_launch(void* const* d_in, const int* in_sizes, int n_in,
                              void* d_out, int out_size, void* d_ws, size_t ws_size,
                              hipStream_t stream) {
    const int*   sup_tok   = (const int*)d_in[0];
    const int*   tgt_tok   = (const int*)d_in[1];
    const int*   blank_sup = (const int*)d_in[2];
    const int*   blank_tgt = (const int*)d_in[3];
    const int*   target_y  = (const int*)d_in[4];
    const float* emb = (const float*)d_in[5];
    const float* WL  = (const float*)d_in[6];
    const float* UL  = (const float*)d_in[7];
    const float* bL  = (const float*)d_in[8];
    const float* WR  = (const float*)d_in[9];
    const float* UR  = (const float*)d_in[10];
    const float* bR  = (const float*)d_in[11];
    const float* Wo  = (const float*)d_in[12];
    const float* Uo  = (const float*)d_in[13];
    const float* bo  = (const float*)d_in[14];
    const float* c0L = (const float*)d_in[15];
    const float* c0R = (const float*)d_in[16];

    float* ws_f = (float*)d_ws;
    float* cA      = ws_f;                         // [2*384*500]
    float* cB      = cA + 2*NSEQ*M;                // [2*384*500]
    float* c_final = cB + 2*NSEQ*M;                // [2*384*500]
    float* env     = c_final + 2*NSEQ*M;           // [384*300]
    float* flags   = env + NSEQ*D;                 // [64]
    float* losses  = flags + B;                    // [64]
    int*   perm    = (int*)(losses + B);           // [2*384]
    int*   lens    = perm + 2*NSEQ;                // [2*384]
    int*   tmax    = lens + 2*NSEQ;                // [12]

    init_c_kernel<<<(2*NSEQ*M + 255)/256, 256, 0, stream>>>(c0L, c0R, cA, c_final);
    sort_kernel<<<1, NSEQ, 0, stream>>>(blank_sup, blank_tgt, perm, lens, tmax);

    for (int s = 0; s < T-1; ++s) {
        const float* csrc = (s & 1) ? cB : cA;
        float*       cdst = (s & 1) ? cA : cB;
        step_kernel<<<2*NCT*NMT, 256, 0, stream>>>(s, csrc, cdst, c_final,
                                                   WL, UL, bL, WR, UR, bR,
                                                   perm, lens, tmax,
                                                   sup_tok, tgt_tok, emb);
    }

    env_kernel<<<NSEQ, 256, 0, stream>>>(c_final, c_final + NSEQ*M, Wo, Uo, bo, env);
    episode_kernel<<<B, 64, 0, stream>>>(env, target_y, flags, losses);
    finalize_kernel<<<1, 64, 0, stream>>>(flags, losses, (float*)d_out);
}

// Round 3
// 10567.799 us; speedup vs baseline: 3.8344x; 1.0421x over previous
//
#include <hip/hip_runtime.h>
#include <math.h>

#define V 13000
#define D 300
#define M 500
#define B 64
#define NW 5
#define T 128
#define NSUP (B*NW)       // 320
#define NSEQ (NSUP + B)   // 384
#define CT 64             // chains per tile (= lanes per wave)
#define NCT 6             // 384/64
#define MB 12             // m per compute block (3 m per wave x 4 waves)
#define NMB 42            // ceil(500/12) -> covers m 0..503 with clamp
#define NKC 8             // K chunks of 100 (3 W-chunks + 5 U-chunks)
#define NCOMP (2*NCT*NMB) // 504 compute blocks
#define NGATH (2*NSEQ)    // 768 gather blocks

__device__ __forceinline__ float sigmoidf_(float x){ return 1.0f/(1.0f+expf(-x)); }

// actT element (dir, k, rank):  actT[ ((dir*8 + k/100)*NSEQ + rank)*100 + k%100 ]
// k in [0,300) = x part (emb row of this step's token); k in [300,800) = c state.

// -------- prologue: c_final = c0 (per global chain), actT0 c-part = c0 (per rank) --------
__global__ void init_kernel(const float* __restrict__ c0L, const float* __restrict__ c0R,
                            float* __restrict__ actT0, float* __restrict__ c_final)
{
    int idx = blockIdx.x*256 + threadIdx.x;      // 2*384*500
    if (idx >= 2*NSEQ*M) return;
    int dir = idx / (NSEQ*M);
    int rem = idx % (NSEQ*M);
    int a = rem / NSEQ;                          // m 0..499
    int r = rem % NSEQ;                          // rank (also reused as chain below)
    float v = dir ? c0R[a] : c0L[a];
    // c_final by (dir, chain=r, m=a)
    c_final[((size_t)dir*NSEQ + r)*M + a] = v;
    // actT0 c-part by (dir, k=300+a, rank=r)
    int k = 300 + a;
    actT0[(((size_t)dir*NKC + (k/100))*NSEQ + r)*100 + (k%100)] = v;
}

// -------- prologue: descending length sort per dir; perm rank->chain, lenR, tile maxes --------
__global__ void sort_kernel(const int* __restrict__ blank_sup, const int* __restrict__ blank_tgt,
                            int* __restrict__ perm, int* __restrict__ lenR, int* __restrict__ tmax)
{
    __shared__ int L0[NSEQ], L1[NSEQ];
    int tid = threadIdx.x;                       // 384 threads
    int blank = (tid < NSUP) ? blank_sup[tid] : blank_tgt[tid - NSUP];
    int l0 = blank, l1 = (T-1) - blank;
    L0[tid] = l0; L1[tid] = l1;
    __syncthreads();
    int r0 = 0, r1 = 0;
    for (int j = 0; j < NSEQ; ++j) {
        int c = L0[j]; r0 += (c > l0) || (c == l0 && j < tid);
        int d = L1[j]; r1 += (d > l1) || (d == l1 && j < tid);
    }
    perm[r0] = tid;        lenR[r0] = l0;
    perm[NSEQ + r1] = tid; lenR[NSEQ + r1] = l1;
    __syncthreads();
    if (tid < 2*NCT) {
        int dir = tid / NCT, t = tid % NCT;
        tmax[tid] = lenR[dir*NSEQ + t*CT];       // descending -> first rank in tile is max
    }
}

// -------- fused per-step kernel: compute blocks (step s) + gather blocks (x for step s+1) ----
__global__ __launch_bounds__(256)
void step_fused(int s,
                const float* __restrict__ actT_cur, float* __restrict__ actT_next,
                float* __restrict__ c_final,
                const float* __restrict__ WL, const float* __restrict__ UL, const float* __restrict__ bL,
                const float* __restrict__ WR, const float* __restrict__ UR, const float* __restrict__ bR,
                const int* __restrict__ perm, const int* __restrict__ lenR, const int* __restrict__ tmax,
                const int* __restrict__ sup_tok, const int* __restrict__ tgt_tok,
                const float* __restrict__ emb)
{
    const int bid = blockIdx.x;
    if (bid < NCOMP) {
        if (s < 0) return;
        const int dir = bid / (NCT*NMB);
        const int r2  = bid % (NCT*NMB);
        const int ct  = r2 / NMB;
        const int mb  = r2 % NMB;
        if (s >= tmax[dir*NCT + ct]) return;     // whole chain-tile finished

        const int wave = threadIdx.x >> 6;
        const int lane = threadIdx.x & 63;
        const int rank = ct*CT + lane;
        const int len  = lenR[dir*NSEQ + rank];
        const int chain = perm[dir*NSEQ + rank];

        const float* Wd = dir ? WR : WL;
        const float* Ud = dir ? UR : UL;
        const float* bias = dir ? bR : bL;

        // rows: 3 m values (wave-uniform), all 3 gates
        int mmu[3]; bool val[3];
        #pragma unroll
        for (int j = 0; j < 3; ++j) {
            int m = mb*MB + wave*3 + j;
            val[j] = (m < M);
            mmu[j] = __builtin_amdgcn_readfirstlane(m < M ? m : (M-1));
        }

        float acc[3][3];
        #pragma unroll
        for (int j = 0; j < 3; ++j)
            #pragma unroll
            for (int g = 0; g < 3; ++g)
                acc[j][g] = bias[g*M + mmu[j]];

        for (int kc = 0; kc < NKC; ++kc) {
            const float4* ap = (const float4*)(actT_cur + (((size_t)dir*NKC + kc)*NSEQ + rank)*100);
            float4 a4[25];
            #pragma unroll
            for (int q = 0; q < 25; ++q) a4[q] = ap[q];

            const float* wb; size_t rs; int ko;
            if (kc < 3) { wb = Wd; rs = D; ko = kc*100; }
            else        { wb = Ud; rs = M; ko = kc*100 - 300; }

            #pragma unroll
            for (int j = 0; j < 3; ++j) {
                if (!val[j]) continue;           // wave-uniform
                #pragma unroll
                for (int g = 0; g < 3; ++g) {
                    const float4* wp = (const float4*)(wb + (size_t)(g*M + mmu[j])*rs + ko);
                    float s0 = 0.f, s1 = 0.f, s2 = 0.f, s3 = 0.f;
                    #pragma unroll
                    for (int q = 0; q < 25; ++q) {
                        float4 w = wp[q];
                        s0 += w.x * a4[q].x;
                        s1 += w.y * a4[q].y;
                        s2 += w.z * a4[q].z;
                        s3 += w.w * a4[q].w;
                    }
                    acc[j][g] += (s0 + s1) + (s2 + s3);
                }
            }
        }

        // cell update: write c into NEXT step's actT (coalesced by rank); snapshot at s==len-1
        #pragma unroll
        for (int j = 0; j < 3; ++j) {
            if (!val[j]) continue;
            const int m = mb*MB + wave*3 + j;    // == mmu[j] here since valid
            const int k = 300 + m;
            const size_t aidx = (((size_t)dir*NKC + (k/100))*NSEQ + rank)*100 + (k%100);
            float cold = actT_cur[aidx];
            float f  = sigmoidf_(acc[j][0]);
            float i2 = sigmoidf_(acc[j][1]);
            float cb = tanhf(acc[j][2]);
            float cn = (s < len) ? (f*cold + i2*cb) : cold;
            actT_next[aidx] = cn;
            if (s == len - 1) c_final[((size_t)dir*NSEQ + chain)*M + m] = cn;
        }
    } else {
        // gather x-part for step s+1 into actT_next
        const int gb = bid - NCOMP;              // 0..767
        const int dir = gb / NSEQ;
        const int rank = gb % NSEQ;
        const int sn = s + 1;
        if (sn >= T-1) return;
        if (sn >= tmax[dir*NCT + rank/CT]) return;
        const int ch = perm[dir*NSEQ + rank];
        const int tpos = dir ? (T-1 - sn) : sn;
        const int tok = (ch < NSUP) ? sup_tok[ch*T + tpos] : tgt_tok[(ch - NSUP)*T + tpos];
        const float* src = emb + (size_t)tok*D;
        for (int k = threadIdx.x; k < D; k += 256) {
            actT_next[(((size_t)dir*NKC + (k/100))*NSEQ + rank)*100 + (k%100)] = src[k];
        }
    }
}

// -------- epilogue: env = tanh(l@Wo^T + r@Uo^T + bo) --------
__global__ void env_kernel(const float* __restrict__ l_states, const float* __restrict__ r_states,
                           const float* __restrict__ Wo, const float* __restrict__ Uo,
                           const float* __restrict__ bo,
                           float* __restrict__ env)
{
    __shared__ __align__(16) float l[M];
    __shared__ __align__(16) float r[M];
    const int i = blockIdx.x;
    const int tid = threadIdx.x;
    for (int m=tid; m<M; m+=blockDim.x){ l[m]=l_states[i*M+m]; r[m]=r_states[i*M+m]; }
    __syncthreads();
    for (int d=tid; d<D; d+=blockDim.x) {
        const float4* wo = reinterpret_cast<const float4*>(Wo + (size_t)d*M);
        const float4* uo = reinterpret_cast<const float4*>(Uo + (size_t)d*M);
        const float4* lv = reinterpret_cast<const float4*>(l);
        const float4* rv = reinterpret_cast<const float4*>(r);
        float acc = bo[d];
        #pragma unroll 5
        for (int q=0; q<M/4; ++q) {
            float4 a=wo[q], bv=lv[q], u=uo[q], rr=rv[q];
            acc += a.x*bv.x + a.y*bv.y + a.z*bv.z + a.w*bv.w;
            acc += u.x*rr.x + u.y*rr.y + u.z*rr.z + u.w*rr.w;
        }
        env[i*D + d] = tanhf(acc);
    }
}

__global__ void episode_kernel(const float* __restrict__ env, const int* __restrict__ target_y,
                               float* __restrict__ flags, float* __restrict__ losses)
{
    const int b = blockIdx.x;
    const int lane = threadIdx.x;
    const float* tgt = env + (size_t)(NSUP + b)*D;

    float tn = 0.f;
    for (int d=lane; d<D; d+=64){ float v=tgt[d]; tn += v*v; }
    for (int off=32; off; off>>=1) tn += __shfl_down(tn, off);
    tn = __shfl(tn, 0);

    float z[NW];
    for (int n=0; n<NW; ++n){
        const float* sup = env + (size_t)(b*NW + n)*D;
        float dot=0.f, sn=0.f;
        for (int d=lane; d<D; d+=64){ float sv=sup[d], tv=tgt[d]; dot+=sv*tv; sn+=sv*sv; }
        for (int off=32; off; off>>=1){ dot += __shfl_down(dot,off); sn += __shfl_down(sn,off); }
        dot = __shfl(dot,0); sn = __shfl(sn,0);
        float denom = fmaxf(sqrtf(sn)*sqrtf(tn), 1e-8f);
        z[n] = dot/denom*10.0f;
    }

    if (lane==0){
        float mx=z[0];
        for(int n=1;n<NW;n++) mx=fmaxf(mx,z[n]);
        float se=0.f; float p[NW];
        for(int n=0;n<NW;n++){ p[n]=expf(z[n]-mx); se+=p[n]; }
        for(int n=0;n<NW;n++) p[n]/=se;
        int am=0; float bv=p[0];
        for(int n=1;n<NW;n++) if(p[n]>bv){bv=p[n];am=n;}
        int y = target_y[b];
        flags[b] = (am==y)?1.0f:0.0f;
        float mx2=p[0]; for(int n=1;n<NW;n++) mx2=fmaxf(mx2,p[n]);
        float se2=0.f; for(int n=0;n<NW;n++) se2+=expf(p[n]-mx2);
        losses[b] = -(p[y]-mx2-logf(se2));
    }
}

__global__ void finalize_kernel(const float* __restrict__ flags, const float* __restrict__ losses,
                                float* __restrict__ out)
{
    const int lane = threadIdx.x; // 64 threads
    float f = flags[lane], l = losses[lane];
    for (int off=32; off; off>>=1){ f += __shfl_down(f,off); l += __shfl_down(l,off); }
    if (lane==0){ out[0] = f/(float)B; out[1] = l/(float)B; }
}

extern "C" void kernel_launch(void* const* d_in, const int* in_sizes, int n_in,
                              void* d_out, int out_size, void* d_ws, size_t ws_size,
                              hipStream_t stream) {
    const int*   sup_tok   = (const int*)d_in[0];
    const int*   tgt_tok   = (const int*)d_in[1];
    const int*   blank_sup = (const int*)d_in[2];
    const int*   blank_tgt = (const int*)d_in[3];
    const int*   target_y  = (const int*)d_in[4];
    const float* emb = (const float*)d_in[5];
    const float* WL  = (const float*)d_in[6];
    const float* UL  = (const float*)d_in[7];
    const float* bL  = (const float*)d_in[8];
    const float* WR  = (const float*)d_in[9];
    const float* UR  = (const float*)d_in[10];
    const float* bR  = (const float*)d_in[11];
    const float* Wo  = (const float*)d_in[12];
    const float* Uo  = (const float*)d_in[13];
    const float* bo  = (const float*)d_in[14];
    const float* c0L = (const float*)d_in[15];
    const float* c0R = (const float*)d_in[16];

    const size_t ACTSZ = (size_t)2*NKC*NSEQ*100;   // 614400 floats per buffer
    float* ws_f = (float*)d_ws;
    float* actT0   = ws_f;                          // buffer 0
    float* actT1   = actT0 + ACTSZ;                 // buffer 1
    float* c_final = actT1 + ACTSZ;                 // [2*384*500]
    float* env     = c_final + 2*NSEQ*M;            // [384*300]
    float* flags   = env + NSEQ*D;                  // [64]
    float* losses  = flags + B;                     // [64]
    int*   perm    = (int*)(losses + B);            // [2*384]
    int*   lenR    = perm + 2*NSEQ;                 // [2*384]
    int*   tmax    = lenR + 2*NSEQ;                 // [12]

    init_kernel<<<(2*NSEQ*M + 255)/256, 256, 0, stream>>>(c0L, c0R, actT0, c_final);
    sort_kernel<<<1, NSEQ, 0, stream>>>(blank_sup, blank_tgt, perm, lenR, tmax);

    // prologue: gather x for step 0 into actT0 (compute blocks no-op at s=-1)
    step_fused<<<NCOMP + NGATH, 256, 0, stream>>>(-1, actT1, actT0, c_final,
                                                  WL, UL, bL, WR, UR, bR,
                                                  perm, lenR, tmax, sup_tok, tgt_tok, emb);
    for (int s = 0; s < T-1; ++s) {
        float* cur  = (s & 1) ? actT1 : actT0;
        float* next = (s & 1) ? actT0 : actT1;
        step_fused<<<NCOMP + NGATH, 256, 0, stream>>>(s, cur, next, c_final,
                                                      WL, UL, bL, WR, UR, bR,
                                                      perm, lenR, tmax, sup_tok, tgt_tok, emb);
    }

    env_kernel<<<NSEQ, 256, 0, stream>>>(c_final, c_final + NSEQ*M, Wo, Uo, bo, env);
    episode_kernel<<<B, 64, 0, stream>>>(env, target_y, flags, losses);
    finalize_kernel<<<1, 64, 0, stream>>>(flags, losses, (float*)d_out);
}